// Round 1
// baseline (135.363 us; speedup 1.0000x reference)
//
#include <hip/hip_runtime.h>
#include <math.h>

// B=32, T=256, C=128, NEIGH=5, TOPK=4.
// wsplit: pre-split W0..2 into bf16 hi/lo pairs (once, tiny).
// proj (no-LDS, barrier-free): direct-fragment MFMA; writes pf/ns PRE-SPLIT
//   (pfh/pfl, nsh/nsl) + f32 ns (for the gather-blend), v transposed split.
// gram: !half = barrier-free direct-fragment G=pf@pf^T; half = LDS-staged
//   blended A (f32 ns gather, identical numerics) + direct split B.
// fused: rowmax conv reads G direct from global (no Gs LDS stage),
//   S/radj prefetched early; softmax -> split-bf16 PV MFMA (vt from L2).

#define TT 256
#define CC 128

using bf16x8 = __attribute__((ext_vector_type(8))) short;
using f32x4  = __attribute__((ext_vector_type(4))) float;

__device__ __forceinline__ short bf_hi(float x) {
    unsigned u = __float_as_uint(x);
    return (short)((u + 0x7FFFu + ((u >> 16) & 1u)) >> 16);
}
__device__ __forceinline__ void bf_split(float x, short& h, short& l) {
    h = bf_hi(x);
    float hf = __uint_as_float(((unsigned)(unsigned short)h) << 16);
    l = bf_hi(x - hf);
}
__device__ __forceinline__ void split8(const float* __restrict__ p, bf16x8& h, bf16x8& l) {
    float4 a = *(const float4*)p;
    float4 b = *(const float4*)(p + 4);
    short sh, sl;
    bf_split(a.x, sh, sl); h[0] = sh; l[0] = sl;
    bf_split(a.y, sh, sl); h[1] = sh; l[1] = sl;
    bf_split(a.z, sh, sl); h[2] = sh; l[2] = sl;
    bf_split(a.w, sh, sl); h[3] = sh; l[3] = sl;
    bf_split(b.x, sh, sl); h[4] = sh; l[4] = sl;
    bf_split(b.y, sh, sl); h[5] = sh; l[5] = sl;
    bf_split(b.z, sh, sl); h[6] = sh; l[6] = sl;
    bf_split(b.w, sh, sl); h[7] = sh; l[7] = sl;
}
__device__ __forceinline__ float max5(float a, float b, float c, float d, float e) {
    return fmaxf(fmaxf(fmaxf(a, b), fmaxf(c, d)), e);
}

// ---- wsplit: W (3x128x128 f32) -> Wh/Wl bf16 pairs. grid (16,3) x 256.
__global__ __launch_bounds__(256) void wsplit_kernel(
    const float* __restrict__ W0, const float* __restrict__ W1, const float* __restrict__ W2,
    short* __restrict__ Wh, short* __restrict__ Wl)
{
    const int m = blockIdx.y;
    const float* __restrict__ W = (m == 0) ? W0 : (m == 1) ? W1 : W2;
    int i = (blockIdx.x * 256 + threadIdx.x) * 4;
    float4 a = *(const float4*)&W[i];
    short4 h, l;
    bf_split(a.x, h.x, l.x); bf_split(a.y, h.y, l.y);
    bf_split(a.z, h.z, l.z); bf_split(a.w, h.w, l.w);
    *(short4*)&Wh[m * CC * CC + i] = h;
    *(short4*)&Wl[m * CC * CC + i] = l;
}

// ---- proj: 32 rows/block, one matrix per blockIdx.y. No LDS in the K-loop:
// A fragments split in-register from x, B fragments loaded pre-split (Wh/Wl).
__global__ __launch_bounds__(256, 3) void proj_kernel(
    const float* __restrict__ x,
    const short* __restrict__ Wh, const short* __restrict__ Wl,
    short* __restrict__ pfh, short* __restrict__ pfl,
    float* __restrict__ nsf, short* __restrict__ nsh, short* __restrict__ nsl,
    short* __restrict__ vt_h, short* __restrict__ vt_l)
{
    __shared__ float ssb[32][4];
    const int tid = threadIdx.x;
    const int row0 = blockIdx.x * 32;
    const int m = blockIdx.y;
    const short* __restrict__ Whm = Wh + m * CC * CC;
    const short* __restrict__ Wlm = Wl + m * CC * CC;
    const int lane = tid & 63, wn = tid >> 6;
    const int quad = lane >> 4, lr = lane & 15;
    f32x4 z4 = {0.f, 0.f, 0.f, 0.f};
    f32x4 acc[2][2] = {{z4, z4}, {z4, z4}};   // [ra][tn]

    #pragma unroll 2
    for (int k0 = 0; k0 < CC; k0 += 32) {
        const int ko = k0 + quad * 8;
        bf16x8 ah[2], al[2], bh[2], bl[2];
        for (int ra = 0; ra < 2; ra++)
            split8(&x[(size_t)(row0 + 16 * ra + lr) * CC + ko], ah[ra], al[ra]);
        for (int tn = 0; tn < 2; tn++) {
            int br = (32 * wn + 16 * tn + lr) * CC + ko;
            bh[tn] = *(const bf16x8*)&Whm[br];
            bl[tn] = *(const bf16x8*)&Wlm[br];
        }
        for (int ra = 0; ra < 2; ra++)
            for (int tn = 0; tn < 2; tn++) {
                acc[ra][tn] = __builtin_amdgcn_mfma_f32_16x16x32_bf16(ah[ra], bh[tn], acc[ra][tn], 0, 0, 0);
                acc[ra][tn] = __builtin_amdgcn_mfma_f32_16x16x32_bf16(ah[ra], bl[tn], acc[ra][tn], 0, 0, 0);
                acc[ra][tn] = __builtin_amdgcn_mfma_f32_16x16x32_bf16(al[ra], bh[tn], acc[ra][tn], 0, 0, 0);
            }
    }
    // D layout: row(m) = 16ra + quad*4 + reg, col(n) = 32wn + 16tn + lr
    if (m < 2) {
        float ssp[2][4];
        for (int ra = 0; ra < 2; ra++)
            for (int reg = 0; reg < 4; reg++) {
                float s = acc[ra][0][reg] * acc[ra][0][reg]
                        + acc[ra][1][reg] * acc[ra][1][reg];
                for (int off = 1; off < 16; off <<= 1) s += __shfl_xor(s, off);
                ssp[ra][reg] = s;
            }
        if (lr == 0)
            for (int ra = 0; ra < 2; ra++)
                for (int reg = 0; reg < 4; reg++)
                    ssb[16 * ra + quad * 4 + reg][wn] = ssp[ra][reg];
        __syncthreads();
        for (int ra = 0; ra < 2; ra++)
            for (int reg = 0; reg < 4; reg++) {
                int ml = 16 * ra + quad * 4 + reg;
                float ss = ssb[ml][0] + ssb[ml][1] + ssb[ml][2] + ssb[ml][3];
                float inv = 1.f / fmaxf(sqrtf(ss), 1e-12f);
                int row = row0 + ml;
                for (int tn = 0; tn < 2; tn++) {
                    int col = 32 * wn + 16 * tn + lr;
                    float val = acc[ra][tn][reg] * inv;
                    short h, l;
                    bf_split(val, h, l);
                    size_t o = (size_t)row * CC + col;
                    if (m == 0) { pfh[o] = h; pfl[o] = l; }
                    else        { nsf[o] = val; nsh[o] = h; nsl[o] = l; }
                }
            }
    } else {
        // v: store transposed split bf16: vt[b][c][t], 4 consecutive t per short4
        for (int ra = 0; ra < 2; ra++) {
            int rowbase = row0 + 16 * ra + quad * 4;
            int b = rowbase >> 8, t0 = rowbase & 255;
            for (int tn = 0; tn < 2; tn++) {
                int c = 32 * wn + 16 * tn + lr;
                short4 h4, l4;
                for (int reg = 0; reg < 4; reg++)
                    bf_split(acc[ra][tn][reg], ((short*)&h4)[reg], ((short*)&l4)[reg]);
                size_t o = ((size_t)b * CC + c) * TT + t0;
                *(short4*)&vt_h[o] = h4;
                *(short4*)&vt_l[o] = l4;
            }
        }
    }
}

// ---- gram: z = b*2 + half. !half: barrier-free direct-fragment pf@pf^T.
// half: LDS-staged blended A (f32 ns gather, as before) + direct split B.
__global__ __launch_bounds__(256, 4) void gram_mfma(
    const short* __restrict__ pfh, const short* __restrict__ pfl,
    const float* __restrict__ nsf,
    const short* __restrict__ nsh, const short* __restrict__ nsl,
    const int* __restrict__ inxs, const float* __restrict__ v_ns,
    const float* __restrict__ g_ns, float* __restrict__ G, float* __restrict__ S)
{
    __shared__ short Ah[64 * 40], Al[64 * 40];
    const int tid = threadIdx.x;
    const int m0 = blockIdx.x * 64, n0 = blockIdx.y * 64;
    const int b = blockIdx.z >> 1, half = blockIdx.z & 1;
    const size_t base = (size_t)b * TT * CC;
    const short* __restrict__ Bhg = (half ? nsh : pfh) + base;
    const short* __restrict__ Blg = (half ? nsl : pfl) + base;
    const int lane = tid & 63, wave = tid >> 6;
    const int wm = wave >> 1, wn = wave & 1;
    const int quad = lane >> 4, lr = lane & 15;
    f32x4 z4 = {0.f, 0.f, 0.f, 0.f};
    f32x4 acc[2][2] = {{z4, z4}, {z4, z4}};
    const int brow0 = (n0 + 32 * wn + lr) * CC;

    if (!half) {
        const short* __restrict__ Ahg = pfh + base;
        const short* __restrict__ Alg = pfl + base;
        const int arow0 = (m0 + 32 * wm + lr) * CC;
        #pragma unroll 2
        for (int k0 = 0; k0 < CC; k0 += 32) {
            const int ko = k0 + quad * 8;
            bf16x8 ah[2], al[2], bh[2], bl[2];
            for (int tm = 0; tm < 2; tm++) {
                ah[tm] = *(const bf16x8*)&Ahg[arow0 + tm * 16 * CC + ko];
                al[tm] = *(const bf16x8*)&Alg[arow0 + tm * 16 * CC + ko];
            }
            for (int tn = 0; tn < 2; tn++) {
                bh[tn] = *(const bf16x8*)&Bhg[brow0 + tn * 16 * CC + ko];
                bl[tn] = *(const bf16x8*)&Blg[brow0 + tn * 16 * CC + ko];
            }
            for (int tm = 0; tm < 2; tm++)
                for (int tn = 0; tn < 2; tn++) {
                    acc[tm][tn] = __builtin_amdgcn_mfma_f32_16x16x32_bf16(ah[tm], bh[tn], acc[tm][tn], 0, 0, 0);
                    acc[tm][tn] = __builtin_amdgcn_mfma_f32_16x16x32_bf16(ah[tm], bl[tn], acc[tm][tn], 0, 0, 0);
                    acc[tm][tn] = __builtin_amdgcn_mfma_f32_16x16x32_bf16(al[tm], bh[tn], acc[tm][tn], 0, 0, 0);
                }
        }
    } else {
        float n2 = v_ns[0]*v_ns[0] + v_ns[1]*v_ns[1] + v_ns[2]*v_ns[2] + v_ns[3]*v_ns[3];
        float sc = g_ns[0] / sqrtf(n2);
        float w0 = sc*v_ns[0], w1 = sc*v_ns[1], w2 = sc*v_ns[2], w3 = sc*v_ns[3];
        int4 id0 = *(const int4*)&inxs[(b * TT + m0 + (tid >> 3)) * 4];
        int4 id1 = *(const int4*)&inxs[(b * TT + m0 + 32 + (tid >> 3)) * 4];
        const float* __restrict__ Nf = nsf + base;

        for (int k0 = 0; k0 < CC; k0 += 32) {
            __syncthreads();
            for (int i = 0; i < 2; i++) {
                int flat = i * 256 + tid, r = flat >> 3, q = (flat & 7) * 4;
                int4 id = i ? id1 : id0;
                float4 aa = *(const float4*)&Nf[id.x * CC + k0 + q];
                float4 ab = *(const float4*)&Nf[id.y * CC + k0 + q];
                float4 ac = *(const float4*)&Nf[id.z * CC + k0 + q];
                float4 ad = *(const float4*)&Nf[id.w * CC + k0 + q];
                float4 a4;
                a4.x = w0*aa.x + w1*ab.x + w2*ac.x + w3*ad.x;
                a4.y = w0*aa.y + w1*ab.y + w2*ac.y + w3*ad.y;
                a4.z = w0*aa.z + w1*ab.z + w2*ac.z + w3*ad.z;
                a4.w = w0*aa.w + w1*ab.w + w2*ac.w + w3*ad.w;
                short4 h4, l4;
                bf_split(a4.x, h4.x, l4.x); bf_split(a4.y, h4.y, l4.y);
                bf_split(a4.z, h4.z, l4.z); bf_split(a4.w, h4.w, l4.w);
                *(short4*)&Ah[r * 40 + q] = h4;
                *(short4*)&Al[r * 40 + q] = l4;
            }
            __syncthreads();
            const int ko = k0 + quad * 8;
            bf16x8 bh[2], bl[2];
            for (int tn = 0; tn < 2; tn++) {
                bh[tn] = *(const bf16x8*)&Bhg[brow0 + tn * 16 * CC + ko];
                bl[tn] = *(const bf16x8*)&Blg[brow0 + tn * 16 * CC + ko];
            }
            for (int tm = 0; tm < 2; tm++) {
                int ar = (32 * wm + 16 * tm + lr) * 40 + quad * 8;
                bf16x8 ah = *(bf16x8*)&Ah[ar];
                bf16x8 al = *(bf16x8*)&Al[ar];
                for (int tn = 0; tn < 2; tn++) {
                    acc[tm][tn] = __builtin_amdgcn_mfma_f32_16x16x32_bf16(ah, bh[tn], acc[tm][tn], 0, 0, 0);
                    acc[tm][tn] = __builtin_amdgcn_mfma_f32_16x16x32_bf16(ah, bl[tn], acc[tm][tn], 0, 0, 0);
                    acc[tm][tn] = __builtin_amdgcn_mfma_f32_16x16x32_bf16(al, bh[tn], acc[tm][tn], 0, 0, 0);
                }
            }
        }
    }
    float* __restrict__ Cb = (half ? S : G) + (size_t)b * TT * TT;
    for (int tm = 0; tm < 2; tm++)
        for (int tn = 0; tn < 2; tn++) {
            int rb = m0 + 32 * wm + 16 * tm + quad * 4;
            int cb = n0 + 32 * wn + 16 * tn + lr;
            for (int reg = 0; reg < 4; reg++)
                Cb[(size_t)(rb + reg) * TT + cb] = acc[tm][tn][reg];
        }
}

// ---- fused: rowmax conv direct from G + prefetched S/mask -> softmax -> PV.
__global__ __launch_bounds__(256, 2) void fused_smax_pv(
    const float* __restrict__ G, const float* __restrict__ S,
    const int* __restrict__ radj, const float* __restrict__ v_pf,
    const float* __restrict__ g_pf,
    const short* __restrict__ vt_h, const short* __restrict__ vt_l,
    float* __restrict__ out)
{
    __shared__ float RM[20 * 256];
    __shared__ short ATH[16 * 264];
    __shared__ short ATL[16 * 264];
    __shared__ float RD[64];
    __shared__ float RMX[64];
    const int tid = threadIdx.x;
    const int xt = blockIdx.x, b = blockIdx.y;
    const int x0 = xt * 16;
    const int rbase = min(max(x0 - 2, 0), TT - 5);
    const int y = tid;
    const size_t sb = (size_t)b * TT * TT;

    // prefetch S + mask early (latency hides under rowmax phase)
    float sadd[16];
    #pragma unroll
    for (int xi = 0; xi < 16; xi++) {
        float s = S[sb + (x0 + xi) * TT + y];
        int a = radj[sb + (x0 + xi) * TT + y];
        sadd[xi] = s + ((a == 0) ? -1e22f : 0.f);
    }
    float n2 = 0.f;
    for (int i = 0; i < 5; i++) n2 += v_pf[i] * v_pf[i];
    float sc = g_pf[0] / sqrtf(n2);
    float wpf[5];
    for (int i = 0; i < 5; i++) wpf[i] = sc * v_pf[i];

    // windowed row-max direct from global G (rows L1-resident): 1280 tasks
    for (int t = 0; t < 5; t++) {
        int task = t * 256 + tid;
        int i = task >> 6, g = task & 63;
        const float* __restrict__ row = &G[sb + (size_t)min(rbase + i, TT - 1) * TT];
        float4 X = *(const float4*)&row[4 * g];
        float m0_, m1_, m2_, m3_;
        if (g == 0) {
            float4 N = *(const float4*)&row[4];
            float mx = fmaxf(fmaxf(X.x, X.y), fmaxf(X.z, X.w));
            m0_ = m1_ = m2_ = fmaxf(mx, N.x);
            m3_ = max5(X.y, X.z, X.w, N.x, N.y);
        } else if (g == 63) {
            float4 P = *(const float4*)&row[248];
            m0_ = max5(P.z, P.w, X.x, X.y, X.z);
            float mx = fmaxf(fmaxf(X.x, X.y), fmaxf(X.z, X.w));
            m1_ = m2_ = m3_ = fmaxf(P.w, mx);
        } else {
            float4 P = *(const float4*)&row[4 * g - 4];
            float4 N = *(const float4*)&row[4 * g + 4];
            m0_ = max5(P.z, P.w, X.x, X.y, X.z);
            m1_ = max5(P.w, X.x, X.y, X.z, X.w);
            m2_ = max5(X.x, X.y, X.z, X.w, N.x);
            m3_ = max5(X.y, X.z, X.w, N.x, N.y);
        }
        float4 o4 = {m0_, m1_, m2_, m3_};
        *(float4*)&RM[i * 256 + 4 * g] = o4;
    }
    __syncthreads();
    float lv[16];
    if (xt > 0 && xt < 15) {
        float rm[20];
        #pragma unroll
        for (int r = 0; r < 20; r++) rm[r] = RM[r * 256 + y];
        #pragma unroll
        for (int xi = 0; xi < 16; xi++) {
            float s = wpf[0] * rm[xi];
            #pragma unroll
            for (int i = 1; i < 5; i++) s = fmaf(wpf[i], rm[xi + i], s);
            lv[xi] = s + sadd[xi];
        }
    } else {
        for (int xi = 0; xi < 16; xi++) {
            int sxr = min(max(x0 + xi - 2, 0), TT - 5) - rbase;
            float s = 0.f;
            for (int i = 0; i < 5; i++) s = fmaf(wpf[i], RM[(sxr + i) * 256 + y], s);
            lv[xi] = s + sadd[xi];
        }
    }
    const int lane = tid & 63, wv = tid >> 6;
    for (int xi = 0; xi < 16; xi++) {
        float v = lv[xi];
        for (int o = 32; o; o >>= 1) v = fmaxf(v, __shfl_xor(v, o));
        if (lane == 0) RMX[xi * 4 + wv] = v;
    }
    __syncthreads();
    for (int xi = 0; xi < 16; xi++) {
        float mx = fmaxf(fmaxf(RMX[xi * 4], RMX[xi * 4 + 1]),
                         fmaxf(RMX[xi * 4 + 2], RMX[xi * 4 + 3]));
        float e = __expf(lv[xi] - mx);
        short h, l;
        bf_split(e, h, l);
        ATH[xi * 264 + y] = h;
        ATL[xi * 264 + y] = l;
        for (int o = 32; o; o >>= 1) e += __shfl_xor(e, o);
        if (lane == 0) RD[xi * 4 + wv] = e;
    }
    __syncthreads();
    // PV: out^T[c,q] tiles. A = vt (global split), B = attn (LDS split).
    const int quad = lane >> 4, lr = lane & 15;
    const int c0 = wv * 32;
    const short* __restrict__ vhb = vt_h + (size_t)b * CC * TT;
    const short* __restrict__ vlb = vt_l + (size_t)b * CC * TT;
    const int ar0 = (c0 + lr) * TT, ar1 = ar0 + 16 * TT;
    f32x4 z4 = {0.f, 0.f, 0.f, 0.f};
    f32x4 acc[2] = {z4, z4};
    #pragma unroll
    for (int k0 = 0; k0 < TT; k0 += 32) {
        int ko = k0 + quad * 8;
        bf16x8 bh = *(bf16x8*)&ATH[lr * 264 + ko];
        bf16x8 bl = *(bf16x8*)&ATL[lr * 264 + ko];
        bf16x8 a0h = *(const bf16x8*)&vhb[ar0 + ko];
        bf16x8 a0l = *(const bf16x8*)&vlb[ar0 + ko];
        bf16x8 a1h = *(const bf16x8*)&vhb[ar1 + ko];
        bf16x8 a1l = *(const bf16x8*)&vlb[ar1 + ko];
        acc[0] = __builtin_amdgcn_mfma_f32_16x16x32_bf16(a0h, bh, acc[0], 0, 0, 0);
        acc[0] = __builtin_amdgcn_mfma_f32_16x16x32_bf16(a0h, bl, acc[0], 0, 0, 0);
        acc[0] = __builtin_amdgcn_mfma_f32_16x16x32_bf16(a0l, bh, acc[0], 0, 0, 0);
        acc[1] = __builtin_amdgcn_mfma_f32_16x16x32_bf16(a1h, bh, acc[1], 0, 0, 0);
        acc[1] = __builtin_amdgcn_mfma_f32_16x16x32_bf16(a1h, bl, acc[1], 0, 0, 0);
        acc[1] = __builtin_amdgcn_mfma_f32_16x16x32_bf16(a1l, bh, acc[1], 0, 0, 0);
    }
    float sm = RD[lr * 4] + RD[lr * 4 + 1] + RD[lr * 4 + 2] + RD[lr * 4 + 3];
    float rinv = 1.f / sm;
    for (int tm = 0; tm < 2; tm++) {
        float4 r;
        r.x = acc[tm][0] * rinv; r.y = acc[tm][1] * rinv;
        r.z = acc[tm][2] * rinv; r.w = acc[tm][3] * rinv;
        *(float4*)&out[(size_t)b * TT * CC + (x0 + lr) * CC + c0 + 16 * tm + quad * 4] = r;
    }
}

extern "C" void kernel_launch(void* const* d_in, const int* in_sizes, int n_in,
                              void* d_out, int out_size, void* d_ws, size_t ws_size,
                              hipStream_t stream) {
    const float* x    = (const float*)d_in[0];
    const int*   radj = (const int*)d_in[1];
    const int*   inxs = (const int*)d_in[2];
    const float* Wpf  = (const float*)d_in[3];
    const float* Wns  = (const float*)d_in[4];
    const float* Wv   = (const float*)d_in[5];
    const float* v_pf = (const float*)d_in[6];
    const float* g_pf = (const float*)d_in[7];
    const float* v_ns = (const float*)d_in[8];
    const float* g_ns = (const float*)d_in[9];
    float* out = (float*)d_out;

    char* base = (char*)d_ws;
    short* pfh  = (short*)(base);                    // 2MB
    short* pfl  = (short*)(base + (2u << 20));       // 2MB
    short* nsh  = (short*)(base + (4u << 20));       // 2MB
    short* nsl  = (short*)(base + (6u << 20));       // 2MB
    float* nsf  = (float*)(base + (8u << 20));       // 4MB
    short* vt_h = (short*)(base + (12u << 20));      // 2MB
    short* vt_l = (short*)(base + (14u << 20));      // 2MB
    float* G    = (float*)(base + (16u << 20));      // 8MB
    float* S    = (float*)(base + (24u << 20));      // 8MB
    short* Wh   = (short*)(base + (32u << 20));      // 96KB
    short* Wl   = (short*)(base + (33u << 20));      // 96KB

    wsplit_kernel<<<dim3(16, 3), 256, 0, stream>>>(Wpf, Wns, Wv, Wh, Wl);
    proj_kernel<<<dim3(256, 3), 256, 0, stream>>>(x, Wh, Wl, pfh, pfl, nsf, nsh, nsl, vt_h, vt_l);
    gram_mfma<<<dim3(4, 4, 64), 256, 0, stream>>>(pfh, pfl, nsf, nsh, nsl, inxs, v_ns, g_ns, G, S);
    fused_smax_pv<<<dim3(16, 32), 256, 0, stream>>>(G, S, radj, v_pf, g_pf,
                                                    vt_h, vt_l, out);
}

// Round 2
// 129.673 us; speedup vs baseline: 1.0439x; 1.0439x over previous
//
#include <hip/hip_runtime.h>
#include <math.h>

// B=32, T=256, C=128, NEIGH=5, TOPK=4.
// R2 = R0 structure (LDS-staged MFMA everywhere, proven 124.8us) with the
// staging VALU removed:
//   wsplit: W pre-split to bf16 hi/lo once (tiny kernel).
//   proj: W tile staged via coalesced short4 copies (no bf_split); x tile
//         still f32->split in-register (small). Epilogue writes pf/ns
//         PRE-SPLIT (pfh/pfl, nsh/nsl) + f32 ns for the gather path.
//   gram: !half A/B and half B staged via coalesced short4 copies from
//         pre-split buffers; half A keeps f32 gather-blend+split (identical
//         numerics).
//   fused: R0 verbatim.

#define TT 256
#define CC 128

using bf16x8 = __attribute__((ext_vector_type(8))) short;
using f32x4  = __attribute__((ext_vector_type(4))) float;

__device__ __forceinline__ short bf_hi(float x) {
    unsigned u = __float_as_uint(x);
    return (short)((u + 0x7FFFu + ((u >> 16) & 1u)) >> 16);
}
__device__ __forceinline__ void bf_split(float x, short& h, short& l) {
    h = bf_hi(x);
    float hf = __uint_as_float(((unsigned)(unsigned short)h) << 16);
    l = bf_hi(x - hf);
}
__device__ __forceinline__ float max5(float a, float b, float c, float d, float e) {
    return fmaxf(fmaxf(fmaxf(a, b), fmaxf(c, d)), e);
}

// ---- wsplit: W (3x128x128 f32) -> Wh/Wl bf16 pairs. grid (16,3) x 256.
__global__ __launch_bounds__(256) void wsplit_kernel(
    const float* __restrict__ W0, const float* __restrict__ W1, const float* __restrict__ W2,
    short* __restrict__ Wh, short* __restrict__ Wl)
{
    const int m = blockIdx.y;
    const float* __restrict__ W = (m == 0) ? W0 : (m == 1) ? W1 : W2;
    int i = (blockIdx.x * 256 + threadIdx.x) * 4;
    float4 a = *(const float4*)&W[i];
    short4 h, l;
    bf_split(a.x, h.x, l.x); bf_split(a.y, h.y, l.y);
    bf_split(a.z, h.z, l.z); bf_split(a.w, h.w, l.w);
    *(short4*)&Wh[m * CC * CC + i] = h;
    *(short4*)&Wl[m * CC * CC + i] = l;
}

// ---- proj: 32 rows/block, one matrix per blockIdx.y, split-bf16 MFMA.
// W tile staged pre-split (coalesced short4 copies); x tile split in-reg.
__global__ __launch_bounds__(256, 4) void proj_kernel(
    const float* __restrict__ x,
    const short* __restrict__ Wh, const short* __restrict__ Wl,
    short* __restrict__ pfh, short* __restrict__ pfl,
    float* __restrict__ nsf, short* __restrict__ nsh, short* __restrict__ nsl,
    short* __restrict__ vt_h, short* __restrict__ vt_l)
{
    __shared__ short Ah[32 * 40], Al[32 * 40];
    __shared__ short Bh[128 * 40], Bl[128 * 40];
    __shared__ float ssb[32][4];
    const int tid = threadIdx.x;
    const int row0 = blockIdx.x * 32;
    const int m = blockIdx.y;
    const short* __restrict__ Whm = Wh + m * CC * CC;
    const short* __restrict__ Wlm = Wl + m * CC * CC;
    const int lane = tid & 63, wn = tid >> 6;
    const int quad = lane >> 4, lr = lane & 15;
    f32x4 z4 = {0.f, 0.f, 0.f, 0.f};
    f32x4 acc[2][2] = {{z4, z4}, {z4, z4}};   // [ra][tn]

    for (int k0 = 0; k0 < CC; k0 += 32) {
        __syncthreads();
        {   // x tile: 32x32 = 256 float4, split in-register
            int r = tid >> 3, q = (tid & 7) * 4;
            float4 a4 = *(const float4*)&x[(row0 + r) * CC + k0 + q];
            short4 h4, l4;
            bf_split(a4.x, h4.x, l4.x); bf_split(a4.y, h4.y, l4.y);
            bf_split(a4.z, h4.z, l4.z); bf_split(a4.w, h4.w, l4.w);
            *(short4*)&Ah[r * 40 + q] = h4; *(short4*)&Al[r * 40 + q] = l4;
        }
        for (int i = 0; i < 4; i++) {  // W tile: 128x32 shorts x2, pure copies
            int flat = i * 256 + tid, r = flat >> 3, q = (flat & 7) * 4;
            *(short4*)&Bh[r * 40 + q] = *(const short4*)&Whm[r * CC + k0 + q];
            *(short4*)&Bl[r * 40 + q] = *(const short4*)&Wlm[r * CC + k0 + q];
        }
        __syncthreads();
        bf16x8 ah[2], al[2], bh[2], bl[2];
        for (int ra = 0; ra < 2; ra++) {
            int ar = (16 * ra + lr) * 40 + quad * 8;
            ah[ra] = *(bf16x8*)&Ah[ar];
            al[ra] = *(bf16x8*)&Al[ar];
        }
        for (int tn = 0; tn < 2; tn++) {
            int br = (32 * wn + 16 * tn + lr) * 40 + quad * 8;
            bh[tn] = *(bf16x8*)&Bh[br];
            bl[tn] = *(bf16x8*)&Bl[br];
        }
        for (int ra = 0; ra < 2; ra++)
            for (int tn = 0; tn < 2; tn++) {
                acc[ra][tn] = __builtin_amdgcn_mfma_f32_16x16x32_bf16(ah[ra], bh[tn], acc[ra][tn], 0, 0, 0);
                acc[ra][tn] = __builtin_amdgcn_mfma_f32_16x16x32_bf16(ah[ra], bl[tn], acc[ra][tn], 0, 0, 0);
                acc[ra][tn] = __builtin_amdgcn_mfma_f32_16x16x32_bf16(al[ra], bh[tn], acc[ra][tn], 0, 0, 0);
            }
    }
    // D layout: row(m) = 16ra + quad*4 + reg, col(n) = 32wn + 16tn + lr
    if (m < 2) {
        float ssp[2][4];
        for (int ra = 0; ra < 2; ra++)
            for (int reg = 0; reg < 4; reg++) {
                float s = acc[ra][0][reg] * acc[ra][0][reg]
                        + acc[ra][1][reg] * acc[ra][1][reg];
                for (int off = 1; off < 16; off <<= 1) s += __shfl_xor(s, off);
                ssp[ra][reg] = s;
            }
        if (lr == 0)
            for (int ra = 0; ra < 2; ra++)
                for (int reg = 0; reg < 4; reg++)
                    ssb[16 * ra + quad * 4 + reg][wn] = ssp[ra][reg];
        __syncthreads();
        for (int ra = 0; ra < 2; ra++)
            for (int reg = 0; reg < 4; reg++) {
                int ml = 16 * ra + quad * 4 + reg;
                float ss = ssb[ml][0] + ssb[ml][1] + ssb[ml][2] + ssb[ml][3];
                float inv = 1.f / fmaxf(sqrtf(ss), 1e-12f);
                int row = row0 + ml;
                for (int tn = 0; tn < 2; tn++) {
                    int col = 32 * wn + 16 * tn + lr;
                    float val = acc[ra][tn][reg] * inv;
                    short h, l;
                    bf_split(val, h, l);
                    size_t o = (size_t)row * CC + col;
                    if (m == 0) { pfh[o] = h; pfl[o] = l; }
                    else        { nsf[o] = val; nsh[o] = h; nsl[o] = l; }
                }
            }
    } else {
        // v: store transposed split bf16: vt[b][c][t], 4 consecutive t per short4
        for (int ra = 0; ra < 2; ra++) {
            int rowbase = row0 + 16 * ra + quad * 4;
            int b = rowbase >> 8, t0 = rowbase & 255;
            for (int tn = 0; tn < 2; tn++) {
                int c = 32 * wn + 16 * tn + lr;
                short4 h4, l4;
                for (int reg = 0; reg < 4; reg++)
                    bf_split(acc[ra][tn][reg], ((short*)&h4)[reg], ((short*)&l4)[reg]);
                size_t o = ((size_t)b * CC + c) * TT + t0;
                *(short4*)&vt_h[o] = h4;
                *(short4*)&vt_l[o] = l4;
            }
        }
    }
}

// ---- gram: z = b*2 + half. LDS-staged MFMA; staging is pure copies except
// the half-A gather-blend (f32, identical numerics to R0).
__global__ __launch_bounds__(256, 4) void gram_mfma(
    const short* __restrict__ pfh, const short* __restrict__ pfl,
    const float* __restrict__ nsf,
    const short* __restrict__ nsh, const short* __restrict__ nsl,
    const int* __restrict__ inxs, const float* __restrict__ v_ns,
    const float* __restrict__ g_ns, float* __restrict__ G, float* __restrict__ S)
{
    __shared__ short Ah[64 * 40], Al[64 * 40], Bh[64 * 40], Bl[64 * 40];
    const int tid = threadIdx.x;
    const int m0 = blockIdx.x * 64, n0 = blockIdx.y * 64;
    const int b = blockIdx.z >> 1, half = blockIdx.z & 1;
    const size_t base = (size_t)b * TT * CC;
    const short* __restrict__ Bhg = (half ? nsh : pfh) + base;
    const short* __restrict__ Blg = (half ? nsl : pfl) + base;

    float w0 = 0.f, w1 = 0.f, w2 = 0.f, w3 = 0.f;
    int4 id0 = {0, 0, 0, 0}, id1 = {0, 0, 0, 0};
    if (half) {
        float n2 = v_ns[0]*v_ns[0] + v_ns[1]*v_ns[1] + v_ns[2]*v_ns[2] + v_ns[3]*v_ns[3];
        float sc = g_ns[0] / sqrtf(n2);
        w0 = sc*v_ns[0]; w1 = sc*v_ns[1]; w2 = sc*v_ns[2]; w3 = sc*v_ns[3];
        id0 = *(const int4*)&inxs[(b * TT + m0 + (tid >> 3)) * 4];
        id1 = *(const int4*)&inxs[(b * TT + m0 + 32 + (tid >> 3)) * 4];
    }

    const int lane = tid & 63, wave = tid >> 6;
    const int wm = wave >> 1, wn = wave & 1;
    const int quad = lane >> 4, lr = lane & 15;
    f32x4 z4 = {0.f, 0.f, 0.f, 0.f};
    f32x4 acc[2][2] = {{z4, z4}, {z4, z4}};
    const short* __restrict__ Ahg = pfh + base;
    const short* __restrict__ Alg = pfl + base;
    const float* __restrict__ Nf = nsf + base;

    for (int k0 = 0; k0 < CC; k0 += 32) {
        __syncthreads();
        if (!half) {
            for (int i = 0; i < 2; i++) {
                int flat = i * 256 + tid, r = flat >> 3, q = (flat & 7) * 4;
                *(short4*)&Ah[r * 40 + q] = *(const short4*)&Ahg[(m0 + r) * CC + k0 + q];
                *(short4*)&Al[r * 40 + q] = *(const short4*)&Alg[(m0 + r) * CC + k0 + q];
                *(short4*)&Bh[r * 40 + q] = *(const short4*)&Bhg[(n0 + r) * CC + k0 + q];
                *(short4*)&Bl[r * 40 + q] = *(const short4*)&Blg[(n0 + r) * CC + k0 + q];
            }
        } else {
            for (int i = 0; i < 2; i++) {
                int flat = i * 256 + tid, r = flat >> 3, q = (flat & 7) * 4;
                int4 id = i ? id1 : id0;
                float4 aa = *(const float4*)&Nf[id.x * CC + k0 + q];
                float4 ab = *(const float4*)&Nf[id.y * CC + k0 + q];
                float4 ac = *(const float4*)&Nf[id.z * CC + k0 + q];
                float4 ad = *(const float4*)&Nf[id.w * CC + k0 + q];
                float4 a4;
                a4.x = w0*aa.x + w1*ab.x + w2*ac.x + w3*ad.x;
                a4.y = w0*aa.y + w1*ab.y + w2*ac.y + w3*ad.y;
                a4.z = w0*aa.z + w1*ab.z + w2*ac.z + w3*ad.z;
                a4.w = w0*aa.w + w1*ab.w + w2*ac.w + w3*ad.w;
                short4 h4, l4;
                bf_split(a4.x, h4.x, l4.x); bf_split(a4.y, h4.y, l4.y);
                bf_split(a4.z, h4.z, l4.z); bf_split(a4.w, h4.w, l4.w);
                *(short4*)&Ah[r * 40 + q] = h4;
                *(short4*)&Al[r * 40 + q] = l4;
                *(short4*)&Bh[r * 40 + q] = *(const short4*)&Bhg[(n0 + r) * CC + k0 + q];
                *(short4*)&Bl[r * 40 + q] = *(const short4*)&Blg[(n0 + r) * CC + k0 + q];
            }
        }
        __syncthreads();
        bf16x8 bh[2], bl[2];
        for (int tn = 0; tn < 2; tn++) {
            int br = (32 * wn + 16 * tn + lr) * 40 + quad * 8;
            bh[tn] = *(bf16x8*)&Bh[br];
            bl[tn] = *(bf16x8*)&Bl[br];
        }
        for (int tm = 0; tm < 2; tm++) {
            int ar = (32 * wm + 16 * tm + lr) * 40 + quad * 8;
            bf16x8 ah = *(bf16x8*)&Ah[ar];
            bf16x8 al = *(bf16x8*)&Al[ar];
            for (int tn = 0; tn < 2; tn++) {
                acc[tm][tn] = __builtin_amdgcn_mfma_f32_16x16x32_bf16(ah, bh[tn], acc[tm][tn], 0, 0, 0);
                acc[tm][tn] = __builtin_amdgcn_mfma_f32_16x16x32_bf16(ah, bl[tn], acc[tm][tn], 0, 0, 0);
                acc[tm][tn] = __builtin_amdgcn_mfma_f32_16x16x32_bf16(al, bh[tn], acc[tm][tn], 0, 0, 0);
            }
        }
    }
    float* __restrict__ Cb = (half ? S : G) + (size_t)b * TT * TT;
    for (int tm = 0; tm < 2; tm++)
        for (int tn = 0; tn < 2; tn++) {
            int rb = m0 + 32 * wm + 16 * tm + quad * 4;
            int cb = n0 + 32 * wn + 16 * tn + lr;
            for (int reg = 0; reg < 4; reg++)
                Cb[(size_t)(rb + reg) * TT + cb] = acc[tm][tn][reg];
        }
}

// ---- fused: vectorized rowmax conv + S + mask -> softmax -> MFMA PV (R0 verbatim).
__global__ __launch_bounds__(256, 2) void fused_smax_pv(
    const float* __restrict__ G, const float* __restrict__ S,
    const int* __restrict__ radj, const float* __restrict__ v_pf,
    const float* __restrict__ g_pf,
    const short* __restrict__ vt_h, const short* __restrict__ vt_l,
    float* __restrict__ out)
{
    __shared__ float Gs[20 * 256];
    __shared__ float RM[20 * 256];
    __shared__ short ATH[16 * 264];
    __shared__ short ATL[16 * 264];
    __shared__ float RD[64];
    __shared__ float RMX[64];
    const int tid = threadIdx.x;
    const int xt = blockIdx.x, b = blockIdx.y;
    const int x0 = xt * 16;
    const int rbase = min(max(x0 - 2, 0), TT - 5);
    for (int i = 0; i < 5; i++) {
        int flat = i * 256 + tid, ri = flat >> 6, q = (flat & 63) * 4;
        int r = min(rbase + ri, TT - 1);
        *(float4*)&Gs[ri * 256 + q] = *(const float4*)&G[(size_t)b * TT * TT + r * TT + q];
    }
    float n2 = 0.f;
    for (int i = 0; i < 5; i++) n2 += v_pf[i] * v_pf[i];
    float sc = g_pf[0] / sqrtf(n2);
    float wpf[5];
    for (int i = 0; i < 5; i++) wpf[i] = sc * v_pf[i];
    __syncthreads();
    // windowed row-max, vectorized: 1280 tasks of 4 cols
    for (int t = 0; t < 5; t++) {
        int task = t * 256 + tid;
        int i = task >> 6, g = task & 63;
        const float* row = &Gs[i * 256];
        float4 X = *(float4*)&row[4 * g];
        float m0_, m1_, m2_, m3_;
        if (g == 0) {
            float4 N = *(float4*)&row[4];
            float mx = fmaxf(fmaxf(X.x, X.y), fmaxf(X.z, X.w));
            m0_ = m1_ = m2_ = fmaxf(mx, N.x);
            m3_ = max5(X.y, X.z, X.w, N.x, N.y);
        } else if (g == 63) {
            float4 P = *(float4*)&row[248];
            m0_ = max5(P.z, P.w, X.x, X.y, X.z);
            float mx = fmaxf(fmaxf(X.x, X.y), fmaxf(X.z, X.w));
            m1_ = m2_ = m3_ = fmaxf(P.w, mx);
        } else {
            float4 P = *(float4*)&row[4 * g - 4];
            float4 N = *(float4*)&row[4 * g + 4];
            m0_ = max5(P.z, P.w, X.x, X.y, X.z);
            m1_ = max5(P.w, X.x, X.y, X.z, X.w);
            m2_ = max5(X.x, X.y, X.z, X.w, N.x);
            m3_ = max5(X.y, X.z, X.w, N.x, N.y);
        }
        float4 o4 = {m0_, m1_, m2_, m3_};
        *(float4*)&RM[i * 256 + 4 * g] = o4;
    }
    __syncthreads();
    const int y = tid;
    const size_t sb = (size_t)b * TT * TT;
    float lv[16];
    if (xt > 0 && xt < 15) {
        float rm[20];
        #pragma unroll
        for (int r = 0; r < 20; r++) rm[r] = RM[r * 256 + y];
        #pragma unroll
        for (int xi = 0; xi < 16; xi++) {
            float s = wpf[0] * rm[xi];
            #pragma unroll
            for (int i = 1; i < 5; i++) s = fmaf(wpf[i], rm[xi + i], s);
            lv[xi] = s;
        }
    } else {
        for (int xi = 0; xi < 16; xi++) {
            int sxr = min(max(x0 + xi - 2, 0), TT - 5) - rbase;
            float s = 0.f;
            for (int i = 0; i < 5; i++) s = fmaf(wpf[i], RM[(sxr + i) * 256 + y], s);
            lv[xi] = s;
        }
    }
    for (int xi = 0; xi < 16; xi++) {
        lv[xi] += S[sb + (x0 + xi) * TT + y];
        if (radj[sb + (x0 + xi) * TT + y] == 0) lv[xi] += -1e22f;
    }
    const int lane = tid & 63, wv = tid >> 6;
    for (int xi = 0; xi < 16; xi++) {
        float v = lv[xi];
        for (int o = 32; o; o >>= 1) v = fmaxf(v, __shfl_xor(v, o));
        if (lane == 0) RMX[xi * 4 + wv] = v;
    }
    __syncthreads();
    for (int xi = 0; xi < 16; xi++) {
        float mx = fmaxf(fmaxf(RMX[xi * 4], RMX[xi * 4 + 1]),
                         fmaxf(RMX[xi * 4 + 2], RMX[xi * 4 + 3]));
        float e = __expf(lv[xi] - mx);
        short h, l;
        bf_split(e, h, l);
        ATH[xi * 264 + y] = h;
        ATL[xi * 264 + y] = l;
        for (int o = 32; o; o >>= 1) e += __shfl_xor(e, o);
        if (lane == 0) RD[xi * 4 + wv] = e;
    }
    __syncthreads();
    // PV: out^T[c,q] tiles. A = vt (global split), B = attn (LDS split).
    const int quad = lane >> 4, lr = lane & 15;
    const int c0 = wv * 32;
    const short* __restrict__ vhb = vt_h + (size_t)b * CC * TT;
    const short* __restrict__ vlb = vt_l + (size_t)b * CC * TT;
    const int ar0 = (c0 + lr) * TT, ar1 = ar0 + 16 * TT;
    f32x4 z4 = {0.f, 0.f, 0.f, 0.f};
    f32x4 acc[2] = {z4, z4};
    #pragma unroll
    for (int k0 = 0; k0 < TT; k0 += 32) {
        int ko = k0 + quad * 8;
        bf16x8 bh = *(bf16x8*)&ATH[lr * 264 + ko];
        bf16x8 bl = *(bf16x8*)&ATL[lr * 264 + ko];
        bf16x8 a0h = *(const bf16x8*)&vhb[ar0 + ko];
        bf16x8 a0l = *(const bf16x8*)&vlb[ar0 + ko];
        bf16x8 a1h = *(const bf16x8*)&vhb[ar1 + ko];
        bf16x8 a1l = *(const bf16x8*)&vlb[ar1 + ko];
        acc[0] = __builtin_amdgcn_mfma_f32_16x16x32_bf16(a0h, bh, acc[0], 0, 0, 0);
        acc[0] = __builtin_amdgcn_mfma_f32_16x16x32_bf16(a0h, bl, acc[0], 0, 0, 0);
        acc[0] = __builtin_amdgcn_mfma_f32_16x16x32_bf16(a0l, bh, acc[0], 0, 0, 0);
        acc[1] = __builtin_amdgcn_mfma_f32_16x16x32_bf16(a1h, bh, acc[1], 0, 0, 0);
        acc[1] = __builtin_amdgcn_mfma_f32_16x16x32_bf16(a1h, bl, acc[1], 0, 0, 0);
        acc[1] = __builtin_amdgcn_mfma_f32_16x16x32_bf16(a1l, bh, acc[1], 0, 0, 0);
    }
    float sm = RD[lr * 4] + RD[lr * 4 + 1] + RD[lr * 4 + 2] + RD[lr * 4 + 3];
    float rinv = 1.f / sm;
    for (int tm = 0; tm < 2; tm++) {
        float4 r;
        r.x = acc[tm][0] * rinv; r.y = acc[tm][1] * rinv;
        r.z = acc[tm][2] * rinv; r.w = acc[tm][3] * rinv;
        *(float4*)&out[(size_t)b * TT * CC + (x0 + lr) * CC + c0 + 16 * tm + quad * 4] = r;
    }
}

extern "C" void kernel_launch(void* const* d_in, const int* in_sizes, int n_in,
                              void* d_out, int out_size, void* d_ws, size_t ws_size,
                              hipStream_t stream) {
    const float* x    = (const float*)d_in[0];
    const int*   radj = (const int*)d_in[1];
    const int*   inxs = (const int*)d_in[2];
    const float* Wpf  = (const float*)d_in[3];
    const float* Wns  = (const float*)d_in[4];
    const float* Wv   = (const float*)d_in[5];
    const float* v_pf = (const float*)d_in[6];
    const float* g_pf = (const float*)d_in[7];
    const float* v_ns = (const float*)d_in[8];
    const float* g_ns = (const float*)d_in[9];
    float* out = (float*)d_out;

    char* base = (char*)d_ws;
    short* pfh  = (short*)(base);                    // 2MB
    short* pfl  = (short*)(base + (2u << 20));       // 2MB
    short* nsh  = (short*)(base + (4u << 20));       // 2MB
    short* nsl  = (short*)(base + (6u << 20));       // 2MB
    float* nsf  = (float*)(base + (8u << 20));       // 4MB
    short* vt_h = (short*)(base + (12u << 20));      // 2MB
    short* vt_l = (short*)(base + (14u << 20));      // 2MB
    float* G    = (float*)(base + (16u << 20));      // 8MB
    float* S    = (float*)(base + (24u << 20));      // 8MB
    short* Wh   = (short*)(base + (32u << 20));      // 96KB
    short* Wl   = (short*)(base + (33u << 20));      // 96KB

    wsplit_kernel<<<dim3(16, 3), 256, 0, stream>>>(Wpf, Wns, Wv, Wh, Wl);
    proj_kernel<<<dim3(256, 3), 256, 0, stream>>>(x, Wh, Wl, pfh, pfl, nsf, nsh, nsl, vt_h, vt_l);
    gram_mfma<<<dim3(4, 4, 64), 256, 0, stream>>>(pfh, pfl, nsf, nsh, nsl, inxs, v_ns, g_ns, G, S);
    fused_smax_pv<<<dim3(16, 32), 256, 0, stream>>>(G, S, radj, v_pf, g_pf,
                                                    vt_h, vt_l, out);
}

// Round 3
// 124.154 us; speedup vs baseline: 1.0903x; 1.0445x over previous
//
#include <hip/hip_runtime.h>
#include <math.h>

// B=32, T=256, C=128, NEIGH=5, TOPK=4.
// R3: TWO kernels.
//  proj (R0-proven staging): pf/ns/v projections via split-bf16 MFMA;
//    epilogue writes pf/ns PRE-SPLIT (pfh/pfl, nsh/nsl) + f32 ns (gather),
//    v transposed split (vt_h/vt_l).
//  fused_all: per (xt,b) block computes its own G-tile (32 rows x 256, direct
//    pre-split fragments, barrier-free) and S-tile (Q gather-blend in LDS,
//    direct ns fragments), then rowmax conv + softmax + PV (all R0-proven).
//  Eliminates: gram kernel, G/S 16MB round-trip, wsplit.

#define TT 256
#define CC 128

using bf16x8 = __attribute__((ext_vector_type(8))) short;
using f32x4  = __attribute__((ext_vector_type(4))) float;

__device__ __forceinline__ short bf_hi(float x) {
    unsigned u = __float_as_uint(x);
    return (short)((u + 0x7FFFu + ((u >> 16) & 1u)) >> 16);
}
__device__ __forceinline__ void bf_split(float x, short& h, short& l) {
    h = bf_hi(x);
    float hf = __uint_as_float(((unsigned)(unsigned short)h) << 16);
    l = bf_hi(x - hf);
}
__device__ __forceinline__ float max5(float a, float b, float c, float d, float e) {
    return fmaxf(fmaxf(fmaxf(a, b), fmaxf(c, d)), e);
}

// ---- proj: 32 rows/block, one matrix per blockIdx.y, split-bf16 MFMA.
// R0-proven LDS staging (W split in staging); R2 epilogue (pre-split outputs).
__global__ __launch_bounds__(256, 4) void proj_kernel(
    const float* __restrict__ x,
    const float* __restrict__ W0, const float* __restrict__ W1, const float* __restrict__ W2,
    short* __restrict__ pfh, short* __restrict__ pfl,
    float* __restrict__ nsf, short* __restrict__ nsh, short* __restrict__ nsl,
    short* __restrict__ vt_h, short* __restrict__ vt_l)
{
    __shared__ short Ah[32 * 40], Al[32 * 40];
    __shared__ short Bh[128 * 40], Bl[128 * 40];
    __shared__ float ssb[32][4];
    const int tid = threadIdx.x;
    const int row0 = blockIdx.x * 32;
    const int m = blockIdx.y;
    const float* __restrict__ W = (m == 0) ? W0 : (m == 1) ? W1 : W2;
    const int lane = tid & 63, wn = tid >> 6;
    const int quad = lane >> 4, lr = lane & 15;
    f32x4 z4 = {0.f, 0.f, 0.f, 0.f};
    f32x4 acc[2][2] = {{z4, z4}, {z4, z4}};   // [ra][tn]

    for (int k0 = 0; k0 < CC; k0 += 32) {
        __syncthreads();
        {   // x tile: 32x32 = 256 float4
            int r = tid >> 3, q = (tid & 7) * 4;
            float4 a4 = *(const float4*)&x[(row0 + r) * CC + k0 + q];
            short4 h4, l4;
            bf_split(a4.x, h4.x, l4.x); bf_split(a4.y, h4.y, l4.y);
            bf_split(a4.z, h4.z, l4.z); bf_split(a4.w, h4.w, l4.w);
            *(short4*)&Ah[r * 40 + q] = h4; *(short4*)&Al[r * 40 + q] = l4;
        }
        for (int i = 0; i < 4; i++) {  // W tile: 128x32 = 1024 float4
            int flat = i * 256 + tid, r = flat >> 3, q = (flat & 7) * 4;
            float4 b4 = *(const float4*)&W[r * CC + k0 + q];
            short4 h4, l4;
            bf_split(b4.x, h4.x, l4.x); bf_split(b4.y, h4.y, l4.y);
            bf_split(b4.z, h4.z, l4.z); bf_split(b4.w, h4.w, l4.w);
            *(short4*)&Bh[r * 40 + q] = h4; *(short4*)&Bl[r * 40 + q] = l4;
        }
        __syncthreads();
        bf16x8 ah[2], al[2], bh[2], bl[2];
        for (int ra = 0; ra < 2; ra++) {
            int ar = (16 * ra + lr) * 40 + quad * 8;
            ah[ra] = *(bf16x8*)&Ah[ar];
            al[ra] = *(bf16x8*)&Al[ar];
        }
        for (int tn = 0; tn < 2; tn++) {
            int br = (32 * wn + 16 * tn + lr) * 40 + quad * 8;
            bh[tn] = *(bf16x8*)&Bh[br];
            bl[tn] = *(bf16x8*)&Bl[br];
        }
        for (int ra = 0; ra < 2; ra++)
            for (int tn = 0; tn < 2; tn++) {
                acc[ra][tn] = __builtin_amdgcn_mfma_f32_16x16x32_bf16(ah[ra], bh[tn], acc[ra][tn], 0, 0, 0);
                acc[ra][tn] = __builtin_amdgcn_mfma_f32_16x16x32_bf16(ah[ra], bl[tn], acc[ra][tn], 0, 0, 0);
                acc[ra][tn] = __builtin_amdgcn_mfma_f32_16x16x32_bf16(al[ra], bh[tn], acc[ra][tn], 0, 0, 0);
            }
    }
    // D layout: row(m) = 16ra + quad*4 + reg, col(n) = 32wn + 16tn + lr
    if (m < 2) {
        float ssp[2][4];
        for (int ra = 0; ra < 2; ra++)
            for (int reg = 0; reg < 4; reg++) {
                float s = acc[ra][0][reg] * acc[ra][0][reg]
                        + acc[ra][1][reg] * acc[ra][1][reg];
                for (int off = 1; off < 16; off <<= 1) s += __shfl_xor(s, off);
                ssp[ra][reg] = s;
            }
        if (lr == 0)
            for (int ra = 0; ra < 2; ra++)
                for (int reg = 0; reg < 4; reg++)
                    ssb[16 * ra + quad * 4 + reg][wn] = ssp[ra][reg];
        __syncthreads();
        for (int ra = 0; ra < 2; ra++)
            for (int reg = 0; reg < 4; reg++) {
                int ml = 16 * ra + quad * 4 + reg;
                float ss = ssb[ml][0] + ssb[ml][1] + ssb[ml][2] + ssb[ml][3];
                float inv = 1.f / fmaxf(sqrtf(ss), 1e-12f);
                int row = row0 + ml;
                for (int tn = 0; tn < 2; tn++) {
                    int col = 32 * wn + 16 * tn + lr;
                    float val = acc[ra][tn][reg] * inv;
                    short h, l;
                    bf_split(val, h, l);
                    size_t o = (size_t)row * CC + col;
                    if (m == 0) { pfh[o] = h; pfl[o] = l; }
                    else        { nsf[o] = val; nsh[o] = h; nsl[o] = l; }
                }
            }
    } else {
        // v: store transposed split bf16: vt[b][c][t], 4 consecutive t per short4
        for (int ra = 0; ra < 2; ra++) {
            int rowbase = row0 + 16 * ra + quad * 4;
            int b = rowbase >> 8, t0 = rowbase & 255;
            for (int tn = 0; tn < 2; tn++) {
                int c = 32 * wn + 16 * tn + lr;
                short4 h4, l4;
                for (int reg = 0; reg < 4; reg++)
                    bf_split(acc[ra][tn][reg], ((short*)&h4)[reg], ((short*)&l4)[reg]);
                size_t o = ((size_t)b * CC + c) * TT + t0;
                *(short4*)&vt_h[o] = h4;
                *(short4*)&vt_l[o] = l4;
            }
        }
    }
}

// ---- fused_all: G-tile + S-tile + rowmax conv + softmax + PV, one kernel.
__global__ __launch_bounds__(256, 2) void fused_all(
    const short* __restrict__ pfh, const short* __restrict__ pfl,
    const float* __restrict__ nsf,
    const short* __restrict__ nsh, const short* __restrict__ nsl,
    const int* __restrict__ inxs, const float* __restrict__ v_ns,
    const float* __restrict__ g_ns,
    const int* __restrict__ radj, const float* __restrict__ v_pf,
    const float* __restrict__ g_pf,
    const short* __restrict__ vt_h, const short* __restrict__ vt_l,
    float* __restrict__ out)
{
    __shared__ float Gs[32 * 260];        // G-tile (reused for S-tile)
    __shared__ float RM[20 * 256];
    __shared__ short Qh[16 * 136], Ql[16 * 136];
    __shared__ short ATH[16 * 264], ATL[16 * 264];
    __shared__ float RD[64], RMX[64];
    const int tid = threadIdx.x;
    const int xt = blockIdx.x, b = blockIdx.y;
    const int x0 = xt * 16;
    const int rbase = min(max(x0 - 2, 0), TT - 5);
    const int a0 = min(rbase, TT - 32);
    const int lane = tid & 63, wv = tid >> 6;
    const int quad = lane >> 4, lr = lane & 15;
    const int y = tid;
    const size_t sb = (size_t)b * TT * TT;
    const size_t base = (size_t)b * TT * CC;
    const short* __restrict__ Ph = pfh + base;
    const short* __restrict__ Pl = pfl + base;
    const short* __restrict__ Nh = nsh + base;
    const short* __restrict__ Nl = nsl + base;

    // prefetch radj mask addends (independent; latency hides under G-phase)
    float sadd[16];
    #pragma unroll
    for (int xi = 0; xi < 16; xi++)
        sadd[xi] = (radj[sb + (x0 + xi) * TT + y] == 0) ? -1e22f : 0.f;

    // ---- G-tile: rows a0..a0+31 x cols 0..255, barrier-free direct fragments
    {
        f32x4 z4 = {0.f, 0.f, 0.f, 0.f};
        f32x4 accg[2][4] = {{z4, z4, z4, z4}, {z4, z4, z4, z4}};
        #pragma unroll
        for (int k0 = 0; k0 < CC; k0 += 32) {
            const int ko = k0 + quad * 8;
            bf16x8 ah[2], al[2], bh[4], bl[4];
            for (int tm = 0; tm < 2; tm++) {
                int ar = (a0 + 16 * tm + lr) * CC + ko;
                ah[tm] = *(const bf16x8*)&Ph[ar];
                al[tm] = *(const bf16x8*)&Pl[ar];
            }
            for (int tn = 0; tn < 4; tn++) {
                int br = (64 * wv + 16 * tn + lr) * CC + ko;
                bh[tn] = *(const bf16x8*)&Ph[br];
                bl[tn] = *(const bf16x8*)&Pl[br];
            }
            for (int tm = 0; tm < 2; tm++)
                for (int tn = 0; tn < 4; tn++) {
                    accg[tm][tn] = __builtin_amdgcn_mfma_f32_16x16x32_bf16(ah[tm], bh[tn], accg[tm][tn], 0, 0, 0);
                    accg[tm][tn] = __builtin_amdgcn_mfma_f32_16x16x32_bf16(ah[tm], bl[tn], accg[tm][tn], 0, 0, 0);
                    accg[tm][tn] = __builtin_amdgcn_mfma_f32_16x16x32_bf16(al[tm], bh[tn], accg[tm][tn], 0, 0, 0);
                }
        }
        for (int tm = 0; tm < 2; tm++)
            for (int tn = 0; tn < 4; tn++)
                for (int reg = 0; reg < 4; reg++)
                    Gs[(16 * tm + quad * 4 + reg) * 260 + 64 * wv + 16 * tn + lr] = accg[tm][tn][reg];
    }
    // ---- stage Q (gather-blend from f32 ns, then split) — 16x128
    {
        float n2 = v_ns[0]*v_ns[0] + v_ns[1]*v_ns[1] + v_ns[2]*v_ns[2] + v_ns[3]*v_ns[3];
        float sc = g_ns[0] / sqrtf(n2);
        float w0 = sc*v_ns[0], w1 = sc*v_ns[1], w2 = sc*v_ns[2], w3 = sc*v_ns[3];
        int r = tid >> 4, c0 = (tid & 15) * 8;
        int4 id = *(const int4*)&inxs[(b * TT + x0 + r) * 4];
        const float* __restrict__ Nf = nsf + base;
        float q[8];
        for (int half = 0; half < 2; half++) {
            float4 aa = *(const float4*)&Nf[id.x * CC + c0 + half * 4];
            float4 ab = *(const float4*)&Nf[id.y * CC + c0 + half * 4];
            float4 ac = *(const float4*)&Nf[id.z * CC + c0 + half * 4];
            float4 ad = *(const float4*)&Nf[id.w * CC + c0 + half * 4];
            q[half*4+0] = w0*aa.x + w1*ab.x + w2*ac.x + w3*ad.x;
            q[half*4+1] = w0*aa.y + w1*ab.y + w2*ac.y + w3*ad.y;
            q[half*4+2] = w0*aa.z + w1*ab.z + w2*ac.z + w3*ad.z;
            q[half*4+3] = w0*aa.w + w1*ab.w + w2*ac.w + w3*ad.w;
        }
        short4 h4, l4;
        for (int half = 0; half < 2; half++) {
            bf_split(q[half*4+0], h4.x, l4.x); bf_split(q[half*4+1], h4.y, l4.y);
            bf_split(q[half*4+2], h4.z, l4.z); bf_split(q[half*4+3], h4.w, l4.w);
            *(short4*)&Qh[r * 136 + c0 + half * 4] = h4;
            *(short4*)&Ql[r * 136 + c0 + half * 4] = l4;
        }
    }
    __syncthreads();
    // ---- windowed row-max from Gs -> RM (R0-proven body, Gs stride 260)
    for (int t = 0; t < 5; t++) {
        int task = t * 256 + tid;
        int i = task >> 6, g = task & 63;
        const float* __restrict__ row = &Gs[(min(rbase + i, TT - 1) - a0) * 260];
        float4 X = *(const float4*)&row[4 * g];
        float m0_, m1_, m2_, m3_;
        if (g == 0) {
            float4 N = *(const float4*)&row[4];
            float mx = fmaxf(fmaxf(X.x, X.y), fmaxf(X.z, X.w));
            m0_ = m1_ = m2_ = fmaxf(mx, N.x);
            m3_ = max5(X.y, X.z, X.w, N.x, N.y);
        } else if (g == 63) {
            float4 P = *(const float4*)&row[248];
            m0_ = max5(P.z, P.w, X.x, X.y, X.z);
            float mx = fmaxf(fmaxf(X.x, X.y), fmaxf(X.z, X.w));
            m1_ = m2_ = m3_ = fmaxf(P.w, mx);
        } else {
            float4 P = *(const float4*)&row[4 * g - 4];
            float4 N = *(const float4*)&row[4 * g + 4];
            m0_ = max5(P.z, P.w, X.x, X.y, X.z);
            m1_ = max5(P.w, X.x, X.y, X.z, X.w);
            m2_ = max5(X.x, X.y, X.z, X.w, N.x);
            m3_ = max5(X.y, X.z, X.w, N.x, N.y);
        }
        float4 o4 = {m0_, m1_, m2_, m3_};
        *(float4*)&RM[i * 256 + 4 * g] = o4;
    }
    __syncthreads();
    // ---- S-tile: Q(16x128, LDS) x ns^T (direct fragments) -> Ss (Gs reuse)
    {
        f32x4 z4 = {0.f, 0.f, 0.f, 0.f};
        f32x4 accs[4] = {z4, z4, z4, z4};
        #pragma unroll
        for (int k0 = 0; k0 < CC; k0 += 32) {
            const int ko = k0 + quad * 8;
            bf16x8 qh = *(bf16x8*)&Qh[lr * 136 + ko];
            bf16x8 ql = *(bf16x8*)&Ql[lr * 136 + ko];
            for (int tn = 0; tn < 4; tn++) {
                int br = (64 * wv + 16 * tn + lr) * CC + ko;
                bf16x8 bh = *(const bf16x8*)&Nh[br];
                bf16x8 bl = *(const bf16x8*)&Nl[br];
                accs[tn] = __builtin_amdgcn_mfma_f32_16x16x32_bf16(qh, bh, accs[tn], 0, 0, 0);
                accs[tn] = __builtin_amdgcn_mfma_f32_16x16x32_bf16(qh, bl, accs[tn], 0, 0, 0);
                accs[tn] = __builtin_amdgcn_mfma_f32_16x16x32_bf16(ql, bh, accs[tn], 0, 0, 0);
            }
        }
        for (int tn = 0; tn < 4; tn++)
            for (int reg = 0; reg < 4; reg++)
                Gs[(quad * 4 + reg) * 260 + 64 * wv + 16 * tn + lr] = accs[tn][reg];
    }
    // ---- conv over RM (overlaps S-phase drain; RM ready)
    float n2 = 0.f;
    for (int i = 0; i < 5; i++) n2 += v_pf[i] * v_pf[i];
    float sc = g_pf[0] / sqrtf(n2);
    float wpf[5];
    for (int i = 0; i < 5; i++) wpf[i] = sc * v_pf[i];
    float lv[16];
    if (xt > 0 && xt < 15) {
        float rm[20];
        #pragma unroll
        for (int r = 0; r < 20; r++) rm[r] = RM[r * 256 + y];
        #pragma unroll
        for (int xi = 0; xi < 16; xi++) {
            float s = wpf[0] * rm[xi];
            #pragma unroll
            for (int i = 1; i < 5; i++) s = fmaf(wpf[i], rm[xi + i], s);
            lv[xi] = s;
        }
    } else {
        for (int xi = 0; xi < 16; xi++) {
            int sxr = min(max(x0 + xi - 2, 0), TT - 5) - rbase;
            float s = 0.f;
            for (int i = 0; i < 5; i++) s = fmaf(wpf[i], RM[(sxr + i) * 256 + y], s);
            lv[xi] = s;
        }
    }
    __syncthreads();
    for (int xi = 0; xi < 16; xi++) {
        lv[xi] += Gs[xi * 260 + y];
        lv[xi] += sadd[xi];
    }
    // ---- softmax (R0-proven)
    for (int xi = 0; xi < 16; xi++) {
        float v = lv[xi];
        for (int o = 32; o; o >>= 1) v = fmaxf(v, __shfl_xor(v, o));
        if (lane == 0) RMX[xi * 4 + wv] = v;
    }
    __syncthreads();
    for (int xi = 0; xi < 16; xi++) {
        float mx = fmaxf(fmaxf(RMX[xi * 4], RMX[xi * 4 + 1]),
                         fmaxf(RMX[xi * 4 + 2], RMX[xi * 4 + 3]));
        float e = __expf(lv[xi] - mx);
        short h, l;
        bf_split(e, h, l);
        ATH[xi * 264 + y] = h;
        ATL[xi * 264 + y] = l;
        for (int o = 32; o; o >>= 1) e += __shfl_xor(e, o);
        if (lane == 0) RD[xi * 4 + wv] = e;
    }
    __syncthreads();
    // ---- PV: out^T[c,q] tiles. A = vt (global split), B = attn (LDS split).
    const int c0 = wv * 32;
    const short* __restrict__ vhb = vt_h + (size_t)b * CC * TT;
    const short* __restrict__ vlb = vt_l + (size_t)b * CC * TT;
    const int ar0 = (c0 + lr) * TT, ar1 = ar0 + 16 * TT;
    f32x4 z4 = {0.f, 0.f, 0.f, 0.f};
    f32x4 acc[2] = {z4, z4};
    #pragma unroll
    for (int k0 = 0; k0 < TT; k0 += 32) {
        int ko = k0 + quad * 8;
        bf16x8 bh = *(bf16x8*)&ATH[lr * 264 + ko];
        bf16x8 bl = *(bf16x8*)&ATL[lr * 264 + ko];
        bf16x8 a0h = *(const bf16x8*)&vhb[ar0 + ko];
        bf16x8 a0l = *(const bf16x8*)&vlb[ar0 + ko];
        bf16x8 a1h = *(const bf16x8*)&vhb[ar1 + ko];
        bf16x8 a1l = *(const bf16x8*)&vlb[ar1 + ko];
        acc[0] = __builtin_amdgcn_mfma_f32_16x16x32_bf16(a0h, bh, acc[0], 0, 0, 0);
        acc[0] = __builtin_amdgcn_mfma_f32_16x16x32_bf16(a0h, bl, acc[0], 0, 0, 0);
        acc[0] = __builtin_amdgcn_mfma_f32_16x16x32_bf16(a0l, bh, acc[0], 0, 0, 0);
        acc[1] = __builtin_amdgcn_mfma_f32_16x16x32_bf16(a1h, bh, acc[1], 0, 0, 0);
        acc[1] = __builtin_amdgcn_mfma_f32_16x16x32_bf16(a1h, bl, acc[1], 0, 0, 0);
        acc[1] = __builtin_amdgcn_mfma_f32_16x16x32_bf16(a1l, bh, acc[1], 0, 0, 0);
    }
    float sm = RD[lr * 4] + RD[lr * 4 + 1] + RD[lr * 4 + 2] + RD[lr * 4 + 3];
    float rinv = 1.f / sm;
    for (int tm = 0; tm < 2; tm++) {
        float4 r;
        r.x = acc[tm][0] * rinv; r.y = acc[tm][1] * rinv;
        r.z = acc[tm][2] * rinv; r.w = acc[tm][3] * rinv;
        *(float4*)&out[(size_t)b * TT * CC + (x0 + lr) * CC + c0 + 16 * tm + quad * 4] = r;
    }
}

extern "C" void kernel_launch(void* const* d_in, const int* in_sizes, int n_in,
                              void* d_out, int out_size, void* d_ws, size_t ws_size,
                              hipStream_t stream) {
    const float* x    = (const float*)d_in[0];
    const int*   radj = (const int*)d_in[1];
    const int*   inxs = (const int*)d_in[2];
    const float* Wpf  = (const float*)d_in[3];
    const float* Wns  = (const float*)d_in[4];
    const float* Wv   = (const float*)d_in[5];
    const float* v_pf = (const float*)d_in[6];
    const float* g_pf = (const float*)d_in[7];
    const float* v_ns = (const float*)d_in[8];
    const float* g_ns = (const float*)d_in[9];
    float* out = (float*)d_out;

    char* base = (char*)d_ws;
    short* pfh  = (short*)(base);                    // 2MB
    short* pfl  = (short*)(base + (2u << 20));       // 2MB
    short* nsh  = (short*)(base + (4u << 20));       // 2MB
    short* nsl  = (short*)(base + (6u << 20));       // 2MB
    float* nsf  = (float*)(base + (8u << 20));       // 4MB
    short* vt_h = (short*)(base + (12u << 20));      // 2MB
    short* vt_l = (short*)(base + (14u << 20));      // 2MB

    proj_kernel<<<dim3(256, 3), 256, 0, stream>>>(x, Wpf, Wns, Wv,
                                                  pfh, pfl, nsf, nsh, nsl, vt_h, vt_l);
    fused_all<<<dim3(16, 32), 256, 0, stream>>>(pfh, pfl, nsf, nsh, nsl,
                                                inxs, v_ns, g_ns, radj, v_pf, g_pf,
                                                vt_h, vt_l, out);
}